// Round 1
// baseline (518.507 us; speedup 1.0000x reference)
//
#include <hip/hip_runtime.h>
#include <hip/hip_bf16.h>

typedef __bf16 bf8_t __attribute__((ext_vector_type(8)));
typedef __bf16 bf4_t __attribute__((ext_vector_type(4)));
typedef float f4_t __attribute__((ext_vector_type(4)));

#define B_ 32
#define T_ 2048
#define C_ 1024
#define H_ 128

// ---------------- W fp32 -> bf16 once, in MFMA-fragment order ----------------
// Wr layout: [cg=24][ks=32][lr=16][kk=32] bf16  (cg = 16-col group over 384
// cols: 0-127=K,128-255=Q,256-383=V; k = ks*32+kk). One wave's B-fragment for
// (cg,ks) is the contiguous 1 KB block, lane(lr,quad) at lr*32+quad*8.
__global__ __launch_bounds__(256) void wconv_kernel(
    const float* __restrict__ Wk, const float* __restrict__ Wq, const float* __restrict__ Wv,
    __bf16* __restrict__ Wr)
{
    const int e  = (blockIdx.x * 256 + threadIdx.x) * 8;   // grid 192 -> 393216 elts
    const int kk = e & 31;                                  // multiple of 8
    const int lr = (e >> 5) & 15;
    const int ks = (e >> 9) & 31;
    const int cg = e >> 14;
    const int col = cg * 16 + lr;
    const int k   = ks * 32 + kk;
    const float* W = (col < 128) ? Wk : (col < 256) ? Wq : Wv;
    const float* p = W + (size_t)(col & 127) * C_ + k;
    float4 f0 = *(const float4*)p;
    float4 f1 = *(const float4*)(p + 4);
    bf8_t o;
    o[0] = (__bf16)f0.x; o[1] = (__bf16)f0.y; o[2] = (__bf16)f0.z; o[3] = (__bf16)f0.w;
    o[4] = (__bf16)f1.x; o[5] = (__bf16)f1.y; o[6] = (__bf16)f1.z; o[7] = (__bf16)f1.w;
    *(bf8_t*)(Wr + e) = o;
}

// ---------------- fused projection: X-resident-in-LDS, W streamed from L2 ----
// grid 1024, block 256 (4 waves), 1 block/CU (132 KB LDS). Whole X tile
// (64 rows x K=1024 bf16) lives in LDS, staged in 8 chunks of K=128 with
// 2-deep register prefetch; W fragments are read straight from L2 in
// fragment-order (no LDS, no k-loop W staging, 8 barriers total).
__global__ __launch_bounds__(256, 1) void proj_kernel(
    const float* __restrict__ x, const __bf16* __restrict__ Wr,
    __bf16* __restrict__ Kb, __bf16* __restrict__ Qb, __bf16* __restrict__ VtG)
{
    __shared__ __bf16 Xs[64][C_ + 8];   // 132 KB, +8 pad keeps 16B rows

    const int m0   = blockIdx.x * 64;
    const int tid  = threadIdx.x;
    const int lane = tid & 63;
    const int wn   = tid >> 6;
    const int lr   = lane & 15;
    const int quad = lane >> 4;
    const int r0   = tid >> 4;          // staging row base (0..15)
    const int kc   = (tid & 15) << 3;   // staging k offset within chunk

    f4_t acc[4][6];
    #pragma unroll
    for (int mi = 0; mi < 4; mi++)
        #pragma unroll
        for (int ni = 0; ni < 6; ni++) acc[mi][ni] = f4_t{0.f, 0.f, 0.f, 0.f};

    float4 bufA[8], bufB[8];

#define LOADC(buf, c) { _Pragma("unroll") \
    for (int i_ = 0; i_ < 4; ++i_) { \
        const float* p_ = x + (size_t)(m0 + r0 + i_ * 16) * C_ + (c) * 128 + kc; \
        buf[2 * i_]     = *(const float4*)p_; \
        buf[2 * i_ + 1] = *(const float4*)(p_ + 4); } }

#define WRITEC(buf, c) { _Pragma("unroll") \
    for (int i_ = 0; i_ < 4; ++i_) { \
        float4 a_ = buf[2 * i_], b_ = buf[2 * i_ + 1]; \
        bf8_t o_; \
        o_[0] = (__bf16)a_.x; o_[1] = (__bf16)a_.y; o_[2] = (__bf16)a_.z; o_[3] = (__bf16)a_.w; \
        o_[4] = (__bf16)b_.x; o_[5] = (__bf16)b_.y; o_[6] = (__bf16)b_.z; o_[7] = (__bf16)b_.w; \
        *(bf8_t*)&Xs[r0 + i_ * 16][(c) * 128 + kc] = o_; } }

#define COMPUTE(c) { _Pragma("unroll") \
    for (int k4_ = 0; k4_ < 4; ++k4_) { \
        const int ks_ = (c) * 4 + k4_; \
        bf8_t xa_[4]; \
        _Pragma("unroll") \
        for (int mi = 0; mi < 4; ++mi) \
            xa_[mi] = *(const bf8_t*)&Xs[mi * 16 + lr][ks_ * 32 + quad * 8]; \
        _Pragma("unroll") \
        for (int ni = 0; ni < 6; ++ni) { \
            bf8_t wb_ = *(const bf8_t*)(Wr + (size_t)((ni * 4 + wn) * 32 + ks_) * 512 + lr * 32 + quad * 8); \
            if (ni < 4) { \
                _Pragma("unroll") \
                for (int mi = 0; mi < 4; ++mi) \
                    acc[mi][ni] = __builtin_amdgcn_mfma_f32_16x16x32_bf16(xa_[mi], wb_, acc[mi][ni], 0, 0, 0); \
            } else { \
                _Pragma("unroll") \
                for (int mi = 0; mi < 4; ++mi) \
                    acc[mi][ni] = __builtin_amdgcn_mfma_f32_16x16x32_bf16(wb_, xa_[mi], acc[mi][ni], 0, 0, 0); \
            } } } }

    LOADC(bufA, 0)
    LOADC(bufB, 1)
    WRITEC(bufA, 0)
    __syncthreads();

    #pragma unroll
    for (int c = 0; c < 8; ++c) {
        // 2-deep prefetch: issue chunk c+2's global loads into the buffer
        // whose contents (chunk c) are already in LDS.
        if (c < 6) { if (c & 1) LOADC(bufB, c + 2) else LOADC(bufA, c + 2) }
        COMPUTE(c)
        if (c < 7) {
            if (c & 1) WRITEC(bufA, c + 1) else WRITEC(bufB, c + 1)
            __syncthreads();
        }
    }

#undef LOADC
#undef WRITEC
#undef COMPUTE

    const int bb = m0 >> 11;
    const int t0 = m0 & (T_ - 1);
    #pragma unroll
    for (int ni = 0; ni < 4; ni++) {
        __bf16* Out = (ni < 2) ? Kb : Qb;
        const int col = (ni & 1) * 64 + wn * 16 + lr;
        #pragma unroll
        for (int mi = 0; mi < 4; mi++)
            for (int r = 0; r < 4; r++) {
                const int row = m0 + mi * 16 + quad * 4 + r;
                Out[(size_t)row * H_ + col] = (__bf16)acc[mi][ni][r];
            }
    }
    #pragma unroll
    for (int ni = 4; ni < 6; ni++)
        for (int mi = 0; mi < 4; mi++) {
            const int tok = t0 + mi * 16 + lr;
            #pragma unroll
            for (int r = 0; r < 4; r++) {
                const int h = (ni - 4) * 64 + wn * 16 + quad * 4 + r;
                VtG[(size_t)bb * H_ * T_ + (size_t)h * T_ + tok] = (__bf16)acc[mi][ni][r];
            }
        }
}

// ---------------- flash attention: prefetched, load-balanced (unchanged) -----
__global__ __launch_bounds__(512, 4) void flash_kernel(
    const __bf16* __restrict__ Qb, const __bf16* __restrict__ Kb,
    const __bf16* __restrict__ VtG, float* __restrict__ Out)
{
    __shared__ __bf16 Ks[64][136];   // [s][h]
    __shared__ __bf16 Vt[128][72];   // [h][s]
    __shared__ __bf16 Ps[128][72];   // [m][s], wave-private slabs

    const int qt = (blockIdx.y < 16) ? (15 - blockIdx.x) : blockIdx.x;
    const int b  = blockIdx.y;
    const size_t kqbase = (size_t)b * T_ * H_;
    const size_t vbase  = (size_t)b * H_ * T_;

    const int tid  = threadIdx.x;
    const int lane = tid & 63;
    const int w    = tid >> 6;
    const int lr   = lane & 15;
    const int quad = lane >> 4;

    bf8_t qf[4];
    {
        const __bf16* qp = Qb + kqbase + (size_t)(qt * 128 + w * 16 + lr) * H_ + quad * 8;
        #pragma unroll
        for (int ks = 0; ks < 4; ks++) qf[ks] = *(const bf8_t*)(qp + ks * 32);
    }

    f4_t o[8];
    #pragma unroll
    for (int n = 0; n < 8; n++) o[n] = f4_t{0.f, 0.f, 0.f, 0.f};
    float ls[4] = {0.f, 0.f, 0.f, 0.f};

    const float sc = 0.03125f * 1.4426950408889634f;   // C^-0.5 * log2(e)
    const int jmax = 2 * qt + 1;

    const int kRow0 = tid >> 4,          kC0 = (tid & 15) << 3;
    const int kRow1 = (tid + 512) >> 4,  kC1 = ((tid + 512) & 15) << 3;
    const int vH0 = tid >> 3,            vS0 = (tid & 7) << 3;
    const int vH1 = (tid + 512) >> 3,    vS1 = ((tid + 512) & 7) << 3;

    bf8_t kr0 = *(const bf8_t*)(Kb + kqbase + (size_t)kRow0 * H_ + kC0);
    bf8_t kr1 = *(const bf8_t*)(Kb + kqbase + (size_t)kRow1 * H_ + kC1);
    bf8_t vr0 = *(const bf8_t*)(VtG + vbase + (size_t)vH0 * T_ + vS0);
    bf8_t vr1 = *(const bf8_t*)(VtG + vbase + (size_t)vH1 * T_ + vS1);

    for (int j = 0; j <= jmax; j++) {
        __syncthreads();
        *(bf8_t*)&Ks[kRow0][kC0] = kr0;
        *(bf8_t*)&Ks[kRow1][kC1] = kr1;
        *(bf8_t*)&Vt[vH0][vS0]   = vr0;
        *(bf8_t*)&Vt[vH1][vS1]   = vr1;
        __syncthreads();
        if (j < jmax) {
            const int s0 = (j + 1) * 64;
            kr0 = *(const bf8_t*)(Kb + kqbase + (size_t)(s0 + kRow0) * H_ + kC0);
            kr1 = *(const bf8_t*)(Kb + kqbase + (size_t)(s0 + kRow1) * H_ + kC1);
            vr0 = *(const bf8_t*)(VtG + vbase + (size_t)vH0 * T_ + s0 + vS0);
            vr1 = *(const bf8_t*)(VtG + vbase + (size_t)vH1 * T_ + s0 + vS1);
        }
        if (j == jmax && w < 4) continue;

        f4_t s4[4];
        #pragma unroll
        for (int n = 0; n < 4; n++) s4[n] = f4_t{0.f, 0.f, 0.f, 0.f};
        #pragma unroll
        for (int ks = 0; ks < 4; ks++)
            for (int n = 0; n < 4; n++) {
                bf8_t kf = *(const bf8_t*)&Ks[n * 16 + lr][ks * 32 + quad * 8];
                s4[n] = __builtin_amdgcn_mfma_f32_16x16x32_bf16(qf[ks], kf, s4[n], 0, 0, 0);
            }

        const bool domask = (j - 2 * qt) == (w >> 2);
        const int rowg = qt * 128 + w * 16 + quad * 4;
        #pragma unroll
        for (int n = 0; n < 4; n++) {
            const int colg = j * 64 + n * 16 + lr;
            #pragma unroll
            for (int r = 0; r < 4; r++) {
                float p = __builtin_exp2f(s4[n][r] * sc);
                if (domask && colg > rowg + r) p = 0.f;
                ls[r] += p;
                Ps[w * 16 + quad * 4 + r][n * 16 + lr] = (__bf16)p;
            }
        }

        #pragma unroll
        for (int ks = 0; ks < 2; ks++) {
            bf8_t pf = *(const bf8_t*)&Ps[w * 16 + lr][ks * 32 + quad * 8];
            #pragma unroll
            for (int n = 0; n < 8; n++) {
                bf8_t vf = *(const bf8_t*)&Vt[n * 16 + lr][ks * 32 + quad * 8];
                o[n] = __builtin_amdgcn_mfma_f32_16x16x32_bf16(pf, vf, o[n], 0, 0, 0);
            }
        }
    }

    float inv[4];
    #pragma unroll
    for (int r = 0; r < 4; r++) {
        float v = ls[r];
        v += __shfl_xor(v, 1);
        v += __shfl_xor(v, 2);
        v += __shfl_xor(v, 4);
        v += __shfl_xor(v, 8);
        inv[r] = 1.f / v;
    }
    #pragma unroll
    for (int n = 0; n < 8; n++) {
        const int col = n * 16 + lr;
        #pragma unroll
        for (int r = 0; r < 4; r++) {
            const int row = qt * 128 + w * 16 + quad * 4 + r;
            Out[kqbase + (size_t)row * H_ + col] = o[n][r] * inv[r];
        }
    }
}

extern "C" void kernel_launch(void* const* d_in, const int* in_sizes, int n_in,
                              void* d_out, int out_size, void* d_ws, size_t ws_size,
                              hipStream_t stream) {
    const float* x  = (const float*)d_in[0];
    const float* Wk = (const float*)d_in[1];
    const float* Wq = (const float*)d_in[2];
    const float* Wv = (const float*)d_in[3];
    float* out = (float*)d_out;

    const size_t n_kqv = (size_t)B_ * T_ * H_;
    __bf16* Kb  = (__bf16*)d_ws;
    __bf16* Qb  = Kb + n_kqv;
    __bf16* VtG = Qb + n_kqv;
    __bf16* Wr  = VtG + n_kqv;   // 768 KB more

    wconv_kernel<<<dim3(192), 256, 0, stream>>>(Wk, Wq, Wv, Wr);
    proj_kernel<<<dim3((B_ * T_) / 64), 256, 0, stream>>>(x, Wr, Kb, Qb, VtG);
    flash_kernel<<<dim3(16, B_), 512, 0, stream>>>(Qb, Kb, VtG, out);
}

// Round 2
// 511.345 us; speedup vs baseline: 1.0140x; 1.0140x over previous
//
#include <hip/hip_runtime.h>
#include <hip/hip_bf16.h>

typedef __bf16 bf8_t __attribute__((ext_vector_type(8)));
typedef __bf16 bf4_t __attribute__((ext_vector_type(4)));
typedef float f4_t __attribute__((ext_vector_type(4)));

#define B_ 32
#define T_ 2048
#define C_ 1024
#define H_ 128

// ---------------- W fp32 -> bf16 once, in MFMA-fragment order ----------------
// Wr layout: [cg=24][ks=32][lr=16][kk=32] bf16  (cg = 16-col group over 384
// cols: 0-127=K,128-255=Q,256-383=V; k = ks*32+kk). One wave's B-fragment for
// (cg,ks) is the contiguous 1 KB block, lane(lr,quad) at lr*32+quad*8.
__global__ __launch_bounds__(256) void wconv_kernel(
    const float* __restrict__ Wk, const float* __restrict__ Wq, const float* __restrict__ Wv,
    __bf16* __restrict__ Wr)
{
    const int e  = (blockIdx.x * 256 + threadIdx.x) * 8;   // grid 192 -> 393216 elts
    const int kk = e & 31;                                  // multiple of 8
    const int lr = (e >> 5) & 15;
    const int ks = (e >> 9) & 31;
    const int cg = e >> 14;
    const int col = cg * 16 + lr;
    const int k   = ks * 32 + kk;
    const float* W = (col < 128) ? Wk : (col < 256) ? Wq : Wv;
    const float* p = W + (size_t)(col & 127) * C_ + k;
    float4 f0 = *(const float4*)p;
    float4 f1 = *(const float4*)(p + 4);
    bf8_t o;
    o[0] = (__bf16)f0.x; o[1] = (__bf16)f0.y; o[2] = (__bf16)f0.z; o[3] = (__bf16)f0.w;
    o[4] = (__bf16)f1.x; o[5] = (__bf16)f1.y; o[6] = (__bf16)f1.z; o[7] = (__bf16)f1.w;
    *(bf8_t*)(Wr + e) = o;
}

// ---------------- fused projection: chunked X-LDS, W streamed from L2 --------
// grid 1024, block 512 (8 waves as 2M x 4N). Tile M=64, N=384.
// X double-buffered in LDS as K=128 chunks (2 x 64 x 136 bf16 = 34.8 KB);
// W fragments read straight from L2 in fragment order (no staging).
// Per-wave acc = 2x6 frags = 48 VGPR -> ~16 waves/CU occupancy.
__global__ __launch_bounds__(512, 4) void proj_kernel(
    const float* __restrict__ x, const __bf16* __restrict__ Wr,
    __bf16* __restrict__ Kb, __bf16* __restrict__ Qb, __bf16* __restrict__ VtG)
{
    __shared__ __bf16 Xs[2][64][136];   // +8 bf16 pad: 2-way max on frag reads

    const int m0   = blockIdx.x * 64;
    const int tid  = threadIdx.x;
    const int lane = tid & 63;
    const int w    = tid >> 6;
    const int wm   = w >> 2;            // 0..1 : row half (32 rows)
    const int wn   = w & 3;             // 0..3 : 16-col group within each ni
    const int lr   = lane & 15;
    const int quad = lane >> 4;

    // staging coords: thread t covers rows {r0, r0+16, r0+32, r0+48}, 4 floats
    // wide at col c4 within the chunk (dense float4 per load instruction).
    const int r0 = tid >> 5;            // 0..15
    const int c4 = (tid & 31) << 2;     // 0..124

    f4_t acc[2][6];
    #pragma unroll
    for (int mi = 0; mi < 2; mi++)
        #pragma unroll
        for (int ni = 0; ni < 6; ni++) acc[mi][ni] = f4_t{0.f, 0.f, 0.f, 0.f};

    float4 pf[4];

#define LOADC(c) { _Pragma("unroll") \
    for (int i_ = 0; i_ < 4; ++i_) \
        pf[i_] = *(const float4*)(x + (size_t)(m0 + r0 + i_ * 16) * C_ + (c) * 128 + c4); }

#define WRITEC(bsel) { _Pragma("unroll") \
    for (int i_ = 0; i_ < 4; ++i_) { \
        float4 f_ = pf[i_]; \
        *(bf4_t*)&Xs[bsel][r0 + i_ * 16][c4] = \
            bf4_t{(__bf16)f_.x, (__bf16)f_.y, (__bf16)f_.z, (__bf16)f_.w}; } }

#define COMPUTE(c, bsel) { _Pragma("unroll") \
    for (int k4_ = 0; k4_ < 4; ++k4_) { \
        bf8_t xa_[2]; \
        _Pragma("unroll") \
        for (int mi = 0; mi < 2; ++mi) \
            xa_[mi] = *(const bf8_t*)&Xs[bsel][wm * 32 + mi * 16 + lr][k4_ * 32 + quad * 8]; \
        _Pragma("unroll") \
        for (int ni = 0; ni < 6; ++ni) { \
            bf8_t wb_ = *(const bf8_t*)(Wr + (size_t)((ni * 4 + wn) * 32 + (c) * 4 + k4_) * 512 + lr * 32 + quad * 8); \
            if (ni < 4) { \
                _Pragma("unroll") \
                for (int mi = 0; mi < 2; ++mi) \
                    acc[mi][ni] = __builtin_amdgcn_mfma_f32_16x16x32_bf16(xa_[mi], wb_, acc[mi][ni], 0, 0, 0); \
            } else { \
                _Pragma("unroll") \
                for (int mi = 0; mi < 2; ++mi) \
                    acc[mi][ni] = __builtin_amdgcn_mfma_f32_16x16x32_bf16(wb_, xa_[mi], acc[mi][ni], 0, 0, 0); \
            } } } }

    LOADC(0)
    WRITEC(0)
    __syncthreads();

    #pragma unroll
    for (int c = 0; c < 8; ++c) {
        if (c < 7) LOADC(c + 1)          // HBM latency hides under COMPUTE
        COMPUTE(c, c & 1)
        if (c < 7) {
            WRITEC((c + 1) & 1)          // other buffer: no race with COMPUTE(c)
            __syncthreads();             // one barrier per chunk (8 total)
        }
    }

#undef LOADC
#undef WRITEC
#undef COMPUTE

    const int bb = m0 >> 11;
    const int t0 = m0 & (T_ - 1);
    #pragma unroll
    for (int ni = 0; ni < 4; ni++) {
        __bf16* Out = (ni < 2) ? Kb : Qb;
        const int col = (ni & 1) * 64 + wn * 16 + lr;
        #pragma unroll
        for (int mi = 0; mi < 2; mi++)
            for (int r = 0; r < 4; r++) {
                const int row = m0 + wm * 32 + mi * 16 + quad * 4 + r;
                Out[(size_t)row * H_ + col] = (__bf16)acc[mi][ni][r];
            }
    }
    #pragma unroll
    for (int ni = 4; ni < 6; ni++)
        for (int mi = 0; mi < 2; mi++) {
            const int tok = t0 + wm * 32 + mi * 16 + lr;
            #pragma unroll
            for (int r = 0; r < 4; r++) {
                const int h = (ni - 4) * 64 + wn * 16 + quad * 4 + r;
                VtG[(size_t)bb * H_ * T_ + (size_t)h * T_ + tok] = (__bf16)acc[mi][ni][r];
            }
        }
}

// ---------------- flash attention: prefetched, load-balanced (unchanged) -----
__global__ __launch_bounds__(512, 4) void flash_kernel(
    const __bf16* __restrict__ Qb, const __bf16* __restrict__ Kb,
    const __bf16* __restrict__ VtG, float* __restrict__ Out)
{
    __shared__ __bf16 Ks[64][136];   // [s][h]
    __shared__ __bf16 Vt[128][72];   // [h][s]
    __shared__ __bf16 Ps[128][72];   // [m][s], wave-private slabs

    const int qt = (blockIdx.y < 16) ? (15 - blockIdx.x) : blockIdx.x;
    const int b  = blockIdx.y;
    const size_t kqbase = (size_t)b * T_ * H_;
    const size_t vbase  = (size_t)b * H_ * T_;

    const int tid  = threadIdx.x;
    const int lane = tid & 63;
    const int w    = tid >> 6;
    const int lr   = lane & 15;
    const int quad = lane >> 4;

    bf8_t qf[4];
    {
        const __bf16* qp = Qb + kqbase + (size_t)(qt * 128 + w * 16 + lr) * H_ + quad * 8;
        #pragma unroll
        for (int ks = 0; ks < 4; ks++) qf[ks] = *(const bf8_t*)(qp + ks * 32);
    }

    f4_t o[8];
    #pragma unroll
    for (int n = 0; n < 8; n++) o[n] = f4_t{0.f, 0.f, 0.f, 0.f};
    float ls[4] = {0.f, 0.f, 0.f, 0.f};

    const float sc = 0.03125f * 1.4426950408889634f;   // C^-0.5 * log2(e)
    const int jmax = 2 * qt + 1;

    const int kRow0 = tid >> 4,          kC0 = (tid & 15) << 3;
    const int kRow1 = (tid + 512) >> 4,  kC1 = ((tid + 512) & 15) << 3;
    const int vH0 = tid >> 3,            vS0 = (tid & 7) << 3;
    const int vH1 = (tid + 512) >> 3,    vS1 = ((tid + 512) & 7) << 3;

    bf8_t kr0 = *(const bf8_t*)(Kb + kqbase + (size_t)kRow0 * H_ + kC0);
    bf8_t kr1 = *(const bf8_t*)(Kb + kqbase + (size_t)kRow1 * H_ + kC1);
    bf8_t vr0 = *(const bf8_t*)(VtG + vbase + (size_t)vH0 * T_ + vS0);
    bf8_t vr1 = *(const bf8_t*)(VtG + vbase + (size_t)vH1 * T_ + vS1);

    for (int j = 0; j <= jmax; j++) {
        __syncthreads();
        *(bf8_t*)&Ks[kRow0][kC0] = kr0;
        *(bf8_t*)&Ks[kRow1][kC1] = kr1;
        *(bf8_t*)&Vt[vH0][vS0]   = vr0;
        *(bf8_t*)&Vt[vH1][vS1]   = vr1;
        __syncthreads();
        if (j < jmax) {
            const int s0 = (j + 1) * 64;
            kr0 = *(const bf8_t*)(Kb + kqbase + (size_t)(s0 + kRow0) * H_ + kC0);
            kr1 = *(const bf8_t*)(Kb + kqbase + (size_t)(s0 + kRow1) * H_ + kC1);
            vr0 = *(const bf8_t*)(VtG + vbase + (size_t)vH0 * T_ + s0 + vS0);
            vr1 = *(const bf8_t*)(VtG + vbase + (size_t)vH1 * T_ + s0 + vS1);
        }
        if (j == jmax && w < 4) continue;

        f4_t s4[4];
        #pragma unroll
        for (int n = 0; n < 4; n++) s4[n] = f4_t{0.f, 0.f, 0.f, 0.f};
        #pragma unroll
        for (int ks = 0; ks < 4; ks++)
            for (int n = 0; n < 4; n++) {
                bf8_t kf = *(const bf8_t*)&Ks[n * 16 + lr][ks * 32 + quad * 8];
                s4[n] = __builtin_amdgcn_mfma_f32_16x16x32_bf16(qf[ks], kf, s4[n], 0, 0, 0);
            }

        const bool domask = (j - 2 * qt) == (w >> 2);
        const int rowg = qt * 128 + w * 16 + quad * 4;
        #pragma unroll
        for (int n = 0; n < 4; n++) {
            const int colg = j * 64 + n * 16 + lr;
            #pragma unroll
            for (int r = 0; r < 4; r++) {
                float p = __builtin_exp2f(s4[n][r] * sc);
                if (domask && colg > rowg + r) p = 0.f;
                ls[r] += p;
                Ps[w * 16 + quad * 4 + r][n * 16 + lr] = (__bf16)p;
            }
        }

        #pragma unroll
        for (int ks = 0; ks < 2; ks++) {
            bf8_t pf = *(const bf8_t*)&Ps[w * 16 + lr][ks * 32 + quad * 8];
            #pragma unroll
            for (int n = 0; n < 8; n++) {
                bf8_t vf = *(const bf8_t*)&Vt[n * 16 + lr][ks * 32 + quad * 8];
                o[n] = __builtin_amdgcn_mfma_f32_16x16x32_bf16(pf, vf, o[n], 0, 0, 0);
            }
        }
    }

    float inv[4];
    #pragma unroll
    for (int r = 0; r < 4; r++) {
        float v = ls[r];
        v += __shfl_xor(v, 1);
        v += __shfl_xor(v, 2);
        v += __shfl_xor(v, 4);
        v += __shfl_xor(v, 8);
        inv[r] = 1.f / v;
    }
    #pragma unroll
    for (int n = 0; n < 8; n++) {
        const int col = n * 16 + lr;
        #pragma unroll
        for (int r = 0; r < 4; r++) {
            const int row = qt * 128 + w * 16 + quad * 4 + r;
            Out[kqbase + (size_t)row * H_ + col] = o[n][r] * inv[r];
        }
    }
}

extern "C" void kernel_launch(void* const* d_in, const int* in_sizes, int n_in,
                              void* d_out, int out_size, void* d_ws, size_t ws_size,
                              hipStream_t stream) {
    const float* x  = (const float*)d_in[0];
    const float* Wk = (const float*)d_in[1];
    const float* Wq = (const float*)d_in[2];
    const float* Wv = (const float*)d_in[3];
    float* out = (float*)d_out;

    const size_t n_kqv = (size_t)B_ * T_ * H_;
    __bf16* Kb  = (__bf16*)d_ws;
    __bf16* Qb  = Kb + n_kqv;
    __bf16* VtG = Qb + n_kqv;
    __bf16* Wr  = VtG + n_kqv;   // 768 KB more

    wconv_kernel<<<dim3(192), 256, 0, stream>>>(Wk, Wq, Wv, Wr);
    proj_kernel<<<dim3((B_ * T_) / 64), 512, 0, stream>>>(x, Wr, Kb, Qb, VtG);
    flash_kernel<<<dim3(16, B_), 512, 0, stream>>>(Qb, Kb, VtG, out);
}

// Round 3
// 478.414 us; speedup vs baseline: 1.0838x; 1.0688x over previous
//
#include <hip/hip_runtime.h>
#include <hip/hip_bf16.h>

typedef __bf16 bf8_t __attribute__((ext_vector_type(8)));
typedef __bf16 bf4_t __attribute__((ext_vector_type(4)));
typedef float f4_t __attribute__((ext_vector_type(4)));

#define B_ 32
#define T_ 2048
#define C_ 1024
#define H_ 128

// ---------------- W fp32 -> bf16 once, in MFMA-fragment order ----------------
// Wr layout: [cg=24][ks=32][lr=16][kk=32] bf16  (cg = 16-col group over 384
// cols: 0-127=K,128-255=Q,256-383=V; k = ks*32+kk). One fragment = 1 KB
// contiguous; lane(lr,quad) data at lr*32+quad*8.
__global__ __launch_bounds__(256) void wconv_kernel(
    const float* __restrict__ Wk, const float* __restrict__ Wq, const float* __restrict__ Wv,
    __bf16* __restrict__ Wr)
{
    const int e  = (blockIdx.x * 256 + threadIdx.x) * 8;   // grid 192 -> 393216 elts
    const int kk = e & 31;                                  // multiple of 8
    const int lr = (e >> 5) & 15;
    const int ks = (e >> 9) & 31;
    const int cg = e >> 14;
    const int col = cg * 16 + lr;
    const int k   = ks * 32 + kk;
    const float* W = (col < 128) ? Wk : (col < 256) ? Wq : Wv;
    const float* p = W + (size_t)(col & 127) * C_ + k;
    float4 f0 = *(const float4*)p;
    float4 f1 = *(const float4*)(p + 4);
    bf8_t o;
    o[0] = (__bf16)f0.x; o[1] = (__bf16)f0.y; o[2] = (__bf16)f0.z; o[3] = (__bf16)f0.w;
    o[4] = (__bf16)f1.x; o[5] = (__bf16)f1.y; o[6] = (__bf16)f1.z; o[7] = (__bf16)f1.w;
    *(bf8_t*)(Wr + e) = o;
}

// ---------------- projection: m97-style 2-phase 128x128 GEMM tiles -----------
// grid 1536 = 512 m-tiles x 3 n-tiles (nt 0:K 1:Q 2:V). 256 thr (4 waves),
// each wave one 64x64 quadrant (acc 4x4). BK=64, 16 k-steps.
// A (x fp32) reg-staged -> cvt -> XOR-swizzled LDS [128][64] bf16 (16 KB).
// B from fragment-order Wr via global_load_lds w16, double-buffered (2x16 KB).
__global__ __launch_bounds__(256) void proj_kernel(
    const float* __restrict__ x, const __bf16* __restrict__ Wr,
    __bf16* __restrict__ Kb, __bf16* __restrict__ Qb, __bf16* __restrict__ VtG)
{
    __shared__ __bf16 As[128 * 64];      // 16 KB, row=64 units, XOR-swizzled
    __shared__ __bf16 Bs[2][16 * 512];   // 2 x 16 KB, 16 fragment chunks each

    const int nt   = blockIdx.x % 3;
    const int m0   = (blockIdx.x / 3) * 128;
    const int tid  = threadIdx.x;
    const int lane = tid & 63;
    const int w    = tid >> 6;
    const int wqm  = w >> 1;             // quadrant row (0..1) -> 64 rows
    const int wqn  = w & 1;              // quadrant col (0..1) -> 64 cols
    const int lr   = lane & 15;
    const int quad = lane >> 4;

    f4_t acc[4][4];
    #pragma unroll
    for (int mi = 0; mi < 4; mi++)
        #pragma unroll
        for (int ni = 0; ni < 4; ni++) acc[mi][ni] = f4_t{0.f, 0.f, 0.f, 0.f};

    float4 pf[8];

    // A tile for k-step t: 128 rows x 64 k (fp32 32 KB -> bf16 16 KB).
    // Chunk u (16B fp32 = 4 floats): row = u>>4, kfloat = (u&15)*4.
#define LOADA(t) { _Pragma("unroll") \
    for (int i_ = 0; i_ < 8; ++i_) { \
        const int u_ = i_ * 256 + tid; \
        pf[i_] = *(const float4*)(x + (size_t)(m0 + (u_ >> 4)) * C_ + (t) * 64 + (u_ & 15) * 4); } }

#define WRITEA { _Pragma("unroll") \
    for (int i_ = 0; i_ < 8; ++i_) { \
        const int u_ = i_ * 256 + tid; \
        const int r_ = u_ >> 4; \
        float4 f_ = pf[i_]; \
        *(bf4_t*)&As[r_ * 64 + ((((u_ & 15) * 4)) ^ ((r_ & 7) * 8))] = \
            bf4_t{(__bf16)f_.x, (__bf16)f_.y, (__bf16)f_.z, (__bf16)f_.w}; } }

    // B tile for k-step t: 16 chunks of 1 KB (cg_local 0..7 x ks_sub 0..1),
    // each chunk a contiguous fragment in Wr. global_load_lds: linear LDS
    // dest (wave base + lane*16), contiguous global src.
#define STAGEB(t, bsel) { _Pragma("unroll") \
    for (int i_ = 0; i_ < 4; ++i_) { \
        const int ci_ = i_ * 4 + w; \
        const __bf16* src_ = Wr + ((size_t)((nt * 8 + (ci_ >> 1)) * 32 + (t) * 2 + (ci_ & 1)) << 9) + lane * 8; \
        __builtin_amdgcn_global_load_lds( \
            (const __attribute__((address_space(1))) void*)src_, \
            (__attribute__((address_space(3))) void*)&Bs[bsel][ci_ << 9], 16, 0, 0); } }

    // prologue: stage tile 0
    LOADA(0)
    STAGEB(0, 0)
    WRITEA                 // compiler inserts vmcnt waits on pf
    __syncthreads();       // drains B(0) global_load_lds too

    #pragma unroll 2
    for (int t = 0; t < 16; ++t) {
        const int bsel = t & 1;
        if (t < 15) {
            LOADA(t + 1)               // HBM loads fly across compute
            STAGEB(t + 1, bsel ^ 1)    // L2 -> LDS, other buffer
        }
        // compute: 2 k-halves x (4 A-frags + 4 B-frags + 16 MFMA)
        #pragma unroll
        for (int kh = 0; kh < 2; ++kh) {
            bf8_t af[4], bfr[4];
            #pragma unroll
            for (int mi = 0; mi < 4; ++mi) {
                const int row = wqm * 64 + mi * 16 + lr;
                af[mi] = *(const bf8_t*)&As[row * 64 + ((kh * 32 + quad * 8) ^ ((row & 7) * 8))];
            }
            #pragma unroll
            for (int ni = 0; ni < 4; ++ni) {
                const int ch = (wqn * 4 + ni) * 2 + kh;
                bfr[ni] = *(const bf8_t*)&Bs[bsel][ch * 512 + lr * 32 + quad * 8];
            }
            if (nt < 2) {
                #pragma unroll
                for (int mi = 0; mi < 4; ++mi)
                    #pragma unroll
                    for (int ni = 0; ni < 4; ++ni)
                        acc[mi][ni] = __builtin_amdgcn_mfma_f32_16x16x32_bf16(af[mi], bfr[ni], acc[mi][ni], 0, 0, 0);
            } else {
                // V: swapped operands -> acc = [h][tok] (transposed output)
                #pragma unroll
                for (int mi = 0; mi < 4; ++mi)
                    #pragma unroll
                    for (int ni = 0; ni < 4; ++ni)
                        acc[mi][ni] = __builtin_amdgcn_mfma_f32_16x16x32_bf16(bfr[ni], af[mi], acc[mi][ni], 0, 0, 0);
            }
        }
        __syncthreads();               // frag reads done; vmcnt(0) drains prefetch
        if (t < 15) {
            WRITEA                     // A(t+1) cvt + swizzled LDS write
            __syncthreads();
        }
    }

#undef LOADA
#undef WRITEA
#undef STAGEB

    if (nt < 2) {
        __bf16* Out = nt ? Qb : Kb;
        #pragma unroll
        for (int ni = 0; ni < 4; ++ni)
            #pragma unroll
            for (int mi = 0; mi < 4; ++mi) {
                const int col = wqn * 64 + ni * 16 + lr;
                #pragma unroll
                for (int r = 0; r < 4; ++r) {
                    const int row = m0 + wqm * 64 + mi * 16 + quad * 4 + r;
                    Out[(size_t)row * H_ + col] = (__bf16)acc[mi][ni][r];
                }
            }
    } else {
        const int bb = m0 >> 11;
        const int t0 = m0 & (T_ - 1);
        #pragma unroll
        for (int ni = 0; ni < 4; ++ni)
            #pragma unroll
            for (int mi = 0; mi < 4; ++mi) {
                const int tok = t0 + wqm * 64 + mi * 16 + lr;
                #pragma unroll
                for (int r = 0; r < 4; ++r) {
                    const int h = wqn * 64 + ni * 16 + quad * 4 + r;
                    VtG[(size_t)bb * H_ * T_ + (size_t)h * T_ + tok] = (__bf16)acc[mi][ni][r];
                }
            }
    }
}

// ---------------- flash attention: prefetched, load-balanced (unchanged) -----
__global__ __launch_bounds__(512, 4) void flash_kernel(
    const __bf16* __restrict__ Qb, const __bf16* __restrict__ Kb,
    const __bf16* __restrict__ VtG, float* __restrict__ Out)
{
    __shared__ __bf16 Ks[64][136];   // [s][h]
    __shared__ __bf16 Vt[128][72];   // [h][s]
    __shared__ __bf16 Ps[128][72];   // [m][s], wave-private slabs

    const int qt = (blockIdx.y < 16) ? (15 - blockIdx.x) : blockIdx.x;
    const int b  = blockIdx.y;
    const size_t kqbase = (size_t)b * T_ * H_;
    const size_t vbase  = (size_t)b * H_ * T_;

    const int tid  = threadIdx.x;
    const int lane = tid & 63;
    const int w    = tid >> 6;
    const int lr   = lane & 15;
    const int quad = lane >> 4;

    bf8_t qf[4];
    {
        const __bf16* qp = Qb + kqbase + (size_t)(qt * 128 + w * 16 + lr) * H_ + quad * 8;
        #pragma unroll
        for (int ks = 0; ks < 4; ks++) qf[ks] = *(const bf8_t*)(qp + ks * 32);
    }

    f4_t o[8];
    #pragma unroll
    for (int n = 0; n < 8; n++) o[n] = f4_t{0.f, 0.f, 0.f, 0.f};
    float ls[4] = {0.f, 0.f, 0.f, 0.f};

    const float sc = 0.03125f * 1.4426950408889634f;   // C^-0.5 * log2(e)
    const int jmax = 2 * qt + 1;

    const int kRow0 = tid >> 4,          kC0 = (tid & 15) << 3;
    const int kRow1 = (tid + 512) >> 4,  kC1 = ((tid + 512) & 15) << 3;
    const int vH0 = tid >> 3,            vS0 = (tid & 7) << 3;
    const int vH1 = (tid + 512) >> 3,    vS1 = ((tid + 512) & 7) << 3;

    bf8_t kr0 = *(const bf8_t*)(Kb + kqbase + (size_t)kRow0 * H_ + kC0);
    bf8_t kr1 = *(const bf8_t*)(Kb + kqbase + (size_t)kRow1 * H_ + kC1);
    bf8_t vr0 = *(const bf8_t*)(VtG + vbase + (size_t)vH0 * T_ + vS0);
    bf8_t vr1 = *(const bf8_t*)(VtG + vbase + (size_t)vH1 * T_ + vS1);

    for (int j = 0; j <= jmax; j++) {
        __syncthreads();
        *(bf8_t*)&Ks[kRow0][kC0] = kr0;
        *(bf8_t*)&Ks[kRow1][kC1] = kr1;
        *(bf8_t*)&Vt[vH0][vS0]   = vr0;
        *(bf8_t*)&Vt[vH1][vS1]   = vr1;
        __syncthreads();
        if (j < jmax) {
            const int s0 = (j + 1) * 64;
            kr0 = *(const bf8_t*)(Kb + kqbase + (size_t)(s0 + kRow0) * H_ + kC0);
            kr1 = *(const bf8_t*)(Kb + kqbase + (size_t)(s0 + kRow1) * H_ + kC1);
            vr0 = *(const bf8_t*)(VtG + vbase + (size_t)vH0 * T_ + s0 + vS0);
            vr1 = *(const bf8_t*)(VtG + vbase + (size_t)vH1 * T_ + s0 + vS1);
        }
        if (j == jmax && w < 4) continue;

        f4_t s4[4];
        #pragma unroll
        for (int n = 0; n < 4; n++) s4[n] = f4_t{0.f, 0.f, 0.f, 0.f};
        #pragma unroll
        for (int ks = 0; ks < 4; ks++)
            for (int n = 0; n < 4; n++) {
                bf8_t kf = *(const bf8_t*)&Ks[n * 16 + lr][ks * 32 + quad * 8];
                s4[n] = __builtin_amdgcn_mfma_f32_16x16x32_bf16(qf[ks], kf, s4[n], 0, 0, 0);
            }

        const bool domask = (j - 2 * qt) == (w >> 2);
        const int rowg = qt * 128 + w * 16 + quad * 4;
        #pragma unroll
        for (int n = 0; n < 4; n++) {
            const int colg = j * 64 + n * 16 + lr;
            #pragma unroll
            for (int r = 0; r < 4; r++) {
                float p = __builtin_exp2f(s4[n][r] * sc);
                if (domask && colg > rowg + r) p = 0.f;
                ls[r] += p;
                Ps[w * 16 + quad * 4 + r][n * 16 + lr] = (__bf16)p;
            }
        }

        #pragma unroll
        for (int ks = 0; ks < 2; ks++) {
            bf8_t pf2 = *(const bf8_t*)&Ps[w * 16 + lr][ks * 32 + quad * 8];
            #pragma unroll
            for (int n = 0; n < 8; n++) {
                bf8_t vf = *(const bf8_t*)&Vt[n * 16 + lr][ks * 32 + quad * 8];
                o[n] = __builtin_amdgcn_mfma_f32_16x16x32_bf16(pf2, vf, o[n], 0, 0, 0);
            }
        }
    }

    float inv[4];
    #pragma unroll
    for (int r = 0; r < 4; r++) {
        float v = ls[r];
        v += __shfl_xor(v, 1);
        v += __shfl_xor(v, 2);
        v += __shfl_xor(v, 4);
        v += __shfl_xor(v, 8);
        inv[r] = 1.f / v;
    }
    #pragma unroll
    for (int n = 0; n < 8; n++) {
        const int col = n * 16 + lr;
        #pragma unroll
        for (int r = 0; r < 4; r++) {
            const int row = qt * 128 + w * 16 + quad * 4 + r;
            Out[kqbase + (size_t)row * H_ + col] = o[n][r] * inv[r];
        }
    }
}

extern "C" void kernel_launch(void* const* d_in, const int* in_sizes, int n_in,
                              void* d_out, int out_size, void* d_ws, size_t ws_size,
                              hipStream_t stream) {
    const float* x  = (const float*)d_in[0];
    const float* Wk = (const float*)d_in[1];
    const float* Wq = (const float*)d_in[2];
    const float* Wv = (const float*)d_in[3];
    float* out = (float*)d_out;

    const size_t n_kqv = (size_t)B_ * T_ * H_;
    __bf16* Kb  = (__bf16*)d_ws;
    __bf16* Qb  = Kb + n_kqv;
    __bf16* VtG = Qb + n_kqv;
    __bf16* Wr  = VtG + n_kqv;   // 768 KB more

    wconv_kernel<<<dim3(192), 256, 0, stream>>>(Wk, Wq, Wv, Wr);
    proj_kernel<<<dim3(512 * 3), 256, 0, stream>>>(x, Wr, Kb, Qb, VtG);
    flash_kernel<<<dim3(16, B_), 512, 0, stream>>>(Qb, Kb, VtG, out);
}

// Round 4
// 472.947 us; speedup vs baseline: 1.0963x; 1.0116x over previous
//
#include <hip/hip_runtime.h>
#include <hip/hip_bf16.h>

typedef __bf16 bf8_t __attribute__((ext_vector_type(8)));
typedef __bf16 bf4_t __attribute__((ext_vector_type(4)));
typedef float f4_t __attribute__((ext_vector_type(4)));

#define B_ 32
#define T_ 2048
#define C_ 1024
#define H_ 128

// ---------------- W fp32 -> bf16 once, in MFMA-fragment order ----------------
// Wr layout: [cg=24][ks=32][lr=16][kk=32] bf16  (cg = 16-col group over 384
// cols: 0-127=K,128-255=Q,256-383=V; k = ks*32+kk). One fragment = 1 KB
// contiguous; lane(lr,quad) data at lr*32+quad*8.
__global__ __launch_bounds__(256) void wconv_kernel(
    const float* __restrict__ Wk, const float* __restrict__ Wq, const float* __restrict__ Wv,
    __bf16* __restrict__ Wr)
{
    const int e  = (blockIdx.x * 256 + threadIdx.x) * 8;   // grid 192 -> 393216 elts
    const int kk = e & 31;                                  // multiple of 8
    const int lr = (e >> 5) & 15;
    const int ks = (e >> 9) & 31;
    const int cg = e >> 14;
    const int col = cg * 16 + lr;
    const int k   = ks * 32 + kk;
    const float* W = (col < 128) ? Wk : (col < 256) ? Wq : Wv;
    const float* p = W + (size_t)(col & 127) * C_ + k;
    float4 f0 = *(const float4*)p;
    float4 f1 = *(const float4*)(p + 4);
    bf8_t o;
    o[0] = (__bf16)f0.x; o[1] = (__bf16)f0.y; o[2] = (__bf16)f0.z; o[3] = (__bf16)f0.w;
    o[4] = (__bf16)f1.x; o[5] = (__bf16)f1.y; o[6] = (__bf16)f1.z; o[7] = (__bf16)f1.w;
    *(bf8_t*)(Wr + e) = o;
}

// ---------------- projection: m97-style 2-phase 128x128 GEMM tiles -----------
// grid 1536 = 512 m-tiles x 3 n-tiles (nt 0:K 1:Q 2:V). 256 thr (4 waves),
// each wave one 64x64 quadrant (acc 4x4). BK=64, 16 k-steps.
// XCD-grouped grid remap: the 3 nt-blocks of one m-tile land on the SAME XCD
// in consecutive slots -> x m-tile fetched from HBM once, L2-served twice.
__global__ __launch_bounds__(256) void proj_kernel(
    const float* __restrict__ x, const __bf16* __restrict__ Wr,
    __bf16* __restrict__ Kb, __bf16* __restrict__ Qb, __bf16* __restrict__ VtG)
{
    __shared__ __bf16 As[128 * 64];      // 16 KB, row=64 units, XOR-swizzled
    __shared__ __bf16 Bs[2][16 * 512];   // 2 x 16 KB, 16 fragment chunks each

    const int bid  = blockIdx.x;
    const int xcd  = bid & 7;
    const int slot = bid >> 3;
    const int nt   = slot % 3;                 // 0:K 1:Q 2:V
    const int m0   = ((slot / 3) * 8 + xcd) * 128;
    const int tid  = threadIdx.x;
    const int lane = tid & 63;
    const int w    = tid >> 6;
    const int wqm  = w >> 1;             // quadrant row (0..1) -> 64 rows
    const int wqn  = w & 1;              // quadrant col (0..1) -> 64 cols
    const int lr   = lane & 15;
    const int quad = lane >> 4;

    f4_t acc[4][4];
    #pragma unroll
    for (int mi = 0; mi < 4; mi++)
        #pragma unroll
        for (int ni = 0; ni < 4; ni++) acc[mi][ni] = f4_t{0.f, 0.f, 0.f, 0.f};

    float4 pf[8];

#define LOADA(t) { _Pragma("unroll") \
    for (int i_ = 0; i_ < 8; ++i_) { \
        const int u_ = i_ * 256 + tid; \
        pf[i_] = *(const float4*)(x + (size_t)(m0 + (u_ >> 4)) * C_ + (t) * 64 + (u_ & 15) * 4); } }

#define WRITEA { _Pragma("unroll") \
    for (int i_ = 0; i_ < 8; ++i_) { \
        const int u_ = i_ * 256 + tid; \
        const int r_ = u_ >> 4; \
        float4 f_ = pf[i_]; \
        *(bf4_t*)&As[r_ * 64 + ((((u_ & 15) * 4)) ^ ((r_ & 7) * 8))] = \
            bf4_t{(__bf16)f_.x, (__bf16)f_.y, (__bf16)f_.z, (__bf16)f_.w}; } }

#define STAGEB(t, bsel) { _Pragma("unroll") \
    for (int i_ = 0; i_ < 4; ++i_) { \
        const int ci_ = i_ * 4 + w; \
        const __bf16* src_ = Wr + ((size_t)((nt * 8 + (ci_ >> 1)) * 32 + (t) * 2 + (ci_ & 1)) << 9) + lane * 8; \
        __builtin_amdgcn_global_load_lds( \
            (const __attribute__((address_space(1))) void*)src_, \
            (__attribute__((address_space(3))) void*)&Bs[bsel][ci_ << 9], 16, 0, 0); } }

    LOADA(0)
    STAGEB(0, 0)
    WRITEA
    __syncthreads();

    #pragma unroll 2
    for (int t = 0; t < 16; ++t) {
        const int bsel = t & 1;
        if (t < 15) {
            LOADA(t + 1)
            STAGEB(t + 1, bsel ^ 1)
        }
        #pragma unroll
        for (int kh = 0; kh < 2; ++kh) {
            bf8_t af[4], bfr[4];
            #pragma unroll
            for (int mi = 0; mi < 4; ++mi) {
                const int row = wqm * 64 + mi * 16 + lr;
                af[mi] = *(const bf8_t*)&As[row * 64 + ((kh * 32 + quad * 8) ^ ((row & 7) * 8))];
            }
            #pragma unroll
            for (int ni = 0; ni < 4; ++ni) {
                const int ch = (wqn * 4 + ni) * 2 + kh;
                bfr[ni] = *(const bf8_t*)&Bs[bsel][ch * 512 + lr * 32 + quad * 8];
            }
            if (nt < 2) {
                #pragma unroll
                for (int mi = 0; mi < 4; ++mi)
                    #pragma unroll
                    for (int ni = 0; ni < 4; ++ni)
                        acc[mi][ni] = __builtin_amdgcn_mfma_f32_16x16x32_bf16(af[mi], bfr[ni], acc[mi][ni], 0, 0, 0);
            } else {
                #pragma unroll
                for (int mi = 0; mi < 4; ++mi)
                    #pragma unroll
                    for (int ni = 0; ni < 4; ++ni)
                        acc[mi][ni] = __builtin_amdgcn_mfma_f32_16x16x32_bf16(bfr[ni], af[mi], acc[mi][ni], 0, 0, 0);
            }
        }
        __syncthreads();
        if (t < 15) {
            WRITEA
            __syncthreads();
        }
    }

#undef LOADA
#undef WRITEA
#undef STAGEB

    if (nt < 2) {
        __bf16* Out = nt ? Qb : Kb;
        #pragma unroll
        for (int ni = 0; ni < 4; ++ni)
            #pragma unroll
            for (int mi = 0; mi < 4; ++mi) {
                const int col = wqn * 64 + ni * 16 + lr;
                #pragma unroll
                for (int r = 0; r < 4; ++r) {
                    const int row = m0 + wqm * 64 + mi * 16 + quad * 4 + r;
                    Out[(size_t)row * H_ + col] = (__bf16)acc[mi][ni][r];
                }
            }
    } else {
        const int bb = m0 >> 11;
        const int t0 = m0 & (T_ - 1);
        #pragma unroll
        for (int ni = 0; ni < 4; ++ni)
            #pragma unroll
            for (int mi = 0; mi < 4; ++mi) {
                const int tok = t0 + wqm * 64 + mi * 16 + lr;
                #pragma unroll
                for (int r = 0; r < 4; ++r) {
                    const int h = wqn * 64 + ni * 16 + quad * 4 + r;
                    VtG[(size_t)bb * H_ * T_ + (size_t)h * T_ + tok] = (__bf16)acc[mi][ni][r];
                }
            }
    }
}

// ---------------- flash attention v2: 4 waves x 32 rows, swapped QK^T --------
// grid (16,32), block 256. Wave w owns q-rows w*32..+31 as 2 m-frags.
// Swapped QK^T (mfma(K,Q)) -> lane holds S[k-consecutive][one q-row=lr]:
// P packs to bf4 ds_write_b64 (4/wave/m vs 16 scalar b16), row-sum is a
// per-lane scalar + 2 shfl_xor. kf/vf LDS reads shared across both m-frags.
__global__ __launch_bounds__(256, 2) void flash_kernel(
    const __bf16* __restrict__ Qb, const __bf16* __restrict__ Kb,
    const __bf16* __restrict__ VtG, float* __restrict__ Out)
{
    __shared__ __bf16 Ks[64][136];   // [s][h]
    __shared__ __bf16 Vt[128][72];   // [h][s]
    __shared__ __bf16 Ps[128][72];   // [q][s], wave-private 32-row slabs

    const int qt = (blockIdx.y < 16) ? (15 - blockIdx.x) : blockIdx.x;
    const int b  = blockIdx.y;
    const size_t kqbase = (size_t)b * T_ * H_;
    const size_t vbase  = (size_t)b * H_ * T_;

    const int tid  = threadIdx.x;    // 0..255
    const int lane = tid & 63;
    const int w    = tid >> 6;       // 0..3
    const int lr   = lane & 15;
    const int quad = lane >> 4;

    // Q fragments (B-operand of swapped QK^T): qf[m][ks]
    bf8_t qf[2][4];
    #pragma unroll
    for (int m = 0; m < 2; m++) {
        const __bf16* qp = Qb + kqbase + (size_t)(qt * 128 + w * 32 + m * 16 + lr) * H_ + quad * 8;
        #pragma unroll
        for (int ks = 0; ks < 4; ks++) qf[m][ks] = *(const bf8_t*)(qp + ks * 32);
    }

    f4_t o[2][8];
    #pragma unroll
    for (int m = 0; m < 2; m++)
        #pragma unroll
        for (int n = 0; n < 8; n++) o[m][n] = f4_t{0.f, 0.f, 0.f, 0.f};
    float ls[2] = {0.f, 0.f};

    const float sc = 0.03125f * 1.4426950408889634f;   // C^-0.5 * log2(e)
    const int jmax = 2 * qt + 1;

    // staging: 256 threads, 4 chunks each for K (64x128) and Vt (128x64)
    int kR[4], kC[4], vH[4], vS[4];
    #pragma unroll
    for (int i = 0; i < 4; i++) {
        const int u = tid + i * 256;
        kR[i] = u >> 4;  kC[i] = (u & 15) << 3;
        vH[i] = u >> 3;  vS[i] = (u & 7) << 3;
    }
    bf8_t kr[4], vr[4];
    #pragma unroll
    for (int i = 0; i < 4; i++) {
        kr[i] = *(const bf8_t*)(Kb + kqbase + (size_t)kR[i] * H_ + kC[i]);
        vr[i] = *(const bf8_t*)(VtG + vbase + (size_t)vH[i] * T_ + vS[i]);
    }

    for (int j = 0; j <= jmax; j++) {
        __syncthreads();
        #pragma unroll
        for (int i = 0; i < 4; i++) {
            *(bf8_t*)&Ks[kR[i]][kC[i]] = kr[i];
            *(bf8_t*)&Vt[vH[i]][vS[i]] = vr[i];
        }
        __syncthreads();
        if (j < jmax) {   // prefetch next tile; hides under compute
            const int s0 = (j + 1) * 64;
            #pragma unroll
            for (int i = 0; i < 4; i++) {
                kr[i] = *(const bf8_t*)(Kb + kqbase + (size_t)(s0 + kR[i]) * H_ + kC[i]);
                vr[i] = *(const bf8_t*)(VtG + vbase + (size_t)vH[i] * T_ + s0 + vS[i]);
            }
        }
        if (j == jmax && w < 2) continue;   // fully masked waves skip compute

        // QK^T swapped: s4[m][n][r] = S[k = j*64+n*16+quad*4+r][q = base+lr]
        f4_t s4[2][4];
        #pragma unroll
        for (int m = 0; m < 2; m++)
            #pragma unroll
            for (int n = 0; n < 4; n++) s4[m][n] = f4_t{0.f, 0.f, 0.f, 0.f};
        #pragma unroll
        for (int ks = 0; ks < 4; ks++)
            #pragma unroll
            for (int n = 0; n < 4; n++) {
                bf8_t kf = *(const bf8_t*)&Ks[n * 16 + lr][ks * 32 + quad * 8];
                s4[0][n] = __builtin_amdgcn_mfma_f32_16x16x32_bf16(kf, qf[0][ks], s4[0][n], 0, 0, 0);
                s4[1][n] = __builtin_amdgcn_mfma_f32_16x16x32_bf16(kf, qf[1][ks], s4[1][n], 0, 0, 0);
            }

        // softmax (per-lane single q-row) + packed P write
        const bool domask = (j == 2 * qt + (w >> 1));
        const int jrel = (j - 2 * qt) * 64;
        #pragma unroll
        for (int m = 0; m < 2; m++) {
            const int qg = w * 32 + m * 16 + lr;   // q-row rel. to q-tile base
            #pragma unroll
            for (int n = 0; n < 4; n++) {
                bf4_t pk;
                #pragma unroll
                for (int r = 0; r < 4; r++) {
                    float p = __builtin_exp2f(s4[m][n][r] * sc);
                    const int kg = jrel + n * 16 + quad * 4 + r;
                    if (domask && kg > qg) p = 0.f;
                    ls[m] += p;
                    pk[r] = (__bf16)p;
                }
                *(bf4_t*)&Ps[w * 32 + m * 16 + lr][n * 16 + quad * 4] = pk;
            }
        }

        // PV: o[m][n] += P[m-rows] * V ; vf shared across both m-frags
        #pragma unroll
        for (int ks = 0; ks < 2; ks++) {
            bf8_t pf0 = *(const bf8_t*)&Ps[w * 32 + lr][ks * 32 + quad * 8];
            bf8_t pf1 = *(const bf8_t*)&Ps[w * 32 + 16 + lr][ks * 32 + quad * 8];
            #pragma unroll
            for (int n = 0; n < 8; n++) {
                bf8_t vf = *(const bf8_t*)&Vt[n * 16 + lr][ks * 32 + quad * 8];
                o[0][n] = __builtin_amdgcn_mfma_f32_16x16x32_bf16(pf0, vf, o[0][n], 0, 0, 0);
                o[1][n] = __builtin_amdgcn_mfma_f32_16x16x32_bf16(pf1, vf, o[1][n], 0, 0, 0);
            }
        }
    }

    // inv rowsum: lane holds sum for q-row (w*32+m*16+lr) spread over quads
    float inv[2][4];
    #pragma unroll
    for (int m = 0; m < 2; m++) {
        float v = ls[m];
        v += __shfl_xor(v, 16);
        v += __shfl_xor(v, 32);
        const float iv = 1.f / v;
        #pragma unroll
        for (int r = 0; r < 4; r++)
            inv[m][r] = __shfl(iv, quad * 4 + r);   // from lane holding that row
    }
    #pragma unroll
    for (int m = 0; m < 2; m++)
        #pragma unroll
        for (int n = 0; n < 8; n++) {
            const int col = n * 16 + lr;
            #pragma unroll
            for (int r = 0; r < 4; r++) {
                const int row = qt * 128 + w * 32 + m * 16 + quad * 4 + r;
                Out[kqbase + (size_t)row * H_ + col] = o[m][n][r] * inv[m][r];
            }
        }
}

extern "C" void kernel_launch(void* const* d_in, const int* in_sizes, int n_in,
                              void* d_out, int out_size, void* d_ws, size_t ws_size,
                              hipStream_t stream) {
    const float* x  = (const float*)d_in[0];
    const float* Wk = (const float*)d_in[1];
    const float* Wq = (const float*)d_in[2];
    const float* Wv = (const float*)d_in[3];
    float* out = (float*)d_out;

    const size_t n_kqv = (size_t)B_ * T_ * H_;
    __bf16* Kb  = (__bf16*)d_ws;
    __bf16* Qb  = Kb + n_kqv;
    __bf16* VtG = Qb + n_kqv;
    __bf16* Wr  = VtG + n_kqv;   // 768 KB more

    wconv_kernel<<<dim3(192), 256, 0, stream>>>(Wk, Wq, Wv, Wr);
    proj_kernel<<<dim3(512 * 3), 256, 0, stream>>>(x, Wr, Kb, Qb, VtG);
    flash_kernel<<<dim3(16, B_), 256, 0, stream>>>(Qb, Kb, VtG, out);
}

// Round 5
// 470.484 us; speedup vs baseline: 1.1021x; 1.0052x over previous
//
#include <hip/hip_runtime.h>
#include <hip/hip_bf16.h>

typedef __bf16 bf8_t __attribute__((ext_vector_type(8)));
typedef __bf16 bf4_t __attribute__((ext_vector_type(4)));
typedef float f4_t __attribute__((ext_vector_type(4)));

#define B_ 32
#define T_ 2048
#define C_ 1024
#define H_ 128

// ---------------- W fp32 -> bf16 once, in MFMA-fragment order ----------------
// Wr layout: [cg=24][ks=32][lr=16][kk=32] bf16  (cg = 16-col group over 384
// cols: 0-127=K,128-255=Q,256-383=V; k = ks*32+kk). One fragment = 1 KB
// contiguous; lane(lr,quad) data at lr*32+quad*8.
__global__ __launch_bounds__(256) void wconv_kernel(
    const float* __restrict__ Wk, const float* __restrict__ Wq, const float* __restrict__ Wv,
    __bf16* __restrict__ Wr)
{
    const int e  = (blockIdx.x * 256 + threadIdx.x) * 8;   // grid 192 -> 393216 elts
    const int kk = e & 31;                                  // multiple of 8
    const int lr = (e >> 5) & 15;
    const int ks = (e >> 9) & 31;
    const int cg = e >> 14;
    const int col = cg * 16 + lr;
    const int k   = ks * 32 + kk;
    const float* W = (col < 128) ? Wk : (col < 256) ? Wq : Wv;
    const float* p = W + (size_t)(col & 127) * C_ + k;
    float4 f0 = *(const float4*)p;
    float4 f1 = *(const float4*)(p + 4);
    bf8_t o;
    o[0] = (__bf16)f0.x; o[1] = (__bf16)f0.y; o[2] = (__bf16)f0.z; o[3] = (__bf16)f0.w;
    o[4] = (__bf16)f1.x; o[5] = (__bf16)f1.y; o[6] = (__bf16)f1.z; o[7] = (__bf16)f1.w;
    *(bf8_t*)(Wr + e) = o;
}

// ---------------- projection: m97-style 2-phase 128x128 GEMM tiles -----------
// grid 1536 = 512 m-tiles x 3 n-tiles (nt 0:K 1:Q 2:V). 256 thr (4 waves),
// each wave one 64x64 quadrant (acc 4x4). BK=64, 16 k-steps.
// XCD-grouped grid remap: the 3 nt-blocks of one m-tile land on the SAME XCD
// in consecutive slots -> x m-tile fetched from HBM once, L2-served twice.
__global__ __launch_bounds__(256) void proj_kernel(
    const float* __restrict__ x, const __bf16* __restrict__ Wr,
    __bf16* __restrict__ Kb, __bf16* __restrict__ Qb, __bf16* __restrict__ VtG)
{
    __shared__ __bf16 As[128 * 64];      // 16 KB, row=64 units, XOR-swizzled
    __shared__ __bf16 Bs[2][16 * 512];   // 2 x 16 KB, 16 fragment chunks each

    const int bid  = blockIdx.x;
    const int xcd  = bid & 7;
    const int slot = bid >> 3;
    const int nt   = slot % 3;                 // 0:K 1:Q 2:V
    const int m0   = ((slot / 3) * 8 + xcd) * 128;
    const int tid  = threadIdx.x;
    const int lane = tid & 63;
    const int w    = tid >> 6;
    const int wqm  = w >> 1;             // quadrant row (0..1) -> 64 rows
    const int wqn  = w & 1;              // quadrant col (0..1) -> 64 cols
    const int lr   = lane & 15;
    const int quad = lane >> 4;

    f4_t acc[4][4];
    #pragma unroll
    for (int mi = 0; mi < 4; mi++)
        #pragma unroll
        for (int ni = 0; ni < 4; ni++) acc[mi][ni] = f4_t{0.f, 0.f, 0.f, 0.f};

    float4 pf[8];

#define LOADA(t) { _Pragma("unroll") \
    for (int i_ = 0; i_ < 8; ++i_) { \
        const int u_ = i_ * 256 + tid; \
        pf[i_] = *(const float4*)(x + (size_t)(m0 + (u_ >> 4)) * C_ + (t) * 64 + (u_ & 15) * 4); } }

#define WRITEA { _Pragma("unroll") \
    for (int i_ = 0; i_ < 8; ++i_) { \
        const int u_ = i_ * 256 + tid; \
        const int r_ = u_ >> 4; \
        float4 f_ = pf[i_]; \
        *(bf4_t*)&As[r_ * 64 + ((((u_ & 15) * 4)) ^ ((r_ & 7) * 8))] = \
            bf4_t{(__bf16)f_.x, (__bf16)f_.y, (__bf16)f_.z, (__bf16)f_.w}; } }

#define STAGEB(t, bsel) { _Pragma("unroll") \
    for (int i_ = 0; i_ < 4; ++i_) { \
        const int ci_ = i_ * 4 + w; \
        const __bf16* src_ = Wr + ((size_t)((nt * 8 + (ci_ >> 1)) * 32 + (t) * 2 + (ci_ & 1)) << 9) + lane * 8; \
        __builtin_amdgcn_global_load_lds( \
            (const __attribute__((address_space(1))) void*)src_, \
            (__attribute__((address_space(3))) void*)&Bs[bsel][ci_ << 9], 16, 0, 0); } }

    LOADA(0)
    STAGEB(0, 0)
    WRITEA
    __syncthreads();

    #pragma unroll 2
    for (int t = 0; t < 16; ++t) {
        const int bsel = t & 1;
        if (t < 15) {
            LOADA(t + 1)
            STAGEB(t + 1, bsel ^ 1)
        }
        #pragma unroll
        for (int kh = 0; kh < 2; ++kh) {
            bf8_t af[4], bfr[4];
            #pragma unroll
            for (int mi = 0; mi < 4; ++mi) {
                const int row = wqm * 64 + mi * 16 + lr;
                af[mi] = *(const bf8_t*)&As[row * 64 + ((kh * 32 + quad * 8) ^ ((row & 7) * 8))];
            }
            #pragma unroll
            for (int ni = 0; ni < 4; ++ni) {
                const int ch = (wqn * 4 + ni) * 2 + kh;
                bfr[ni] = *(const bf8_t*)&Bs[bsel][ch * 512 + lr * 32 + quad * 8];
            }
            if (nt < 2) {
                #pragma unroll
                for (int mi = 0; mi < 4; ++mi)
                    #pragma unroll
                    for (int ni = 0; ni < 4; ++ni)
                        acc[mi][ni] = __builtin_amdgcn_mfma_f32_16x16x32_bf16(af[mi], bfr[ni], acc[mi][ni], 0, 0, 0);
            } else {
                #pragma unroll
                for (int mi = 0; mi < 4; ++mi)
                    #pragma unroll
                    for (int ni = 0; ni < 4; ++ni)
                        acc[mi][ni] = __builtin_amdgcn_mfma_f32_16x16x32_bf16(bfr[ni], af[mi], acc[mi][ni], 0, 0, 0);
            }
        }
        __syncthreads();
        if (t < 15) {
            WRITEA
            __syncthreads();
        }
    }

#undef LOADA
#undef WRITEA
#undef STAGEB

    if (nt < 2) {
        __bf16* Out = nt ? Qb : Kb;
        #pragma unroll
        for (int ni = 0; ni < 4; ++ni)
            #pragma unroll
            for (int mi = 0; mi < 4; ++mi) {
                const int col = wqn * 64 + ni * 16 + lr;
                #pragma unroll
                for (int r = 0; r < 4; ++r) {
                    const int row = m0 + wqm * 64 + mi * 16 + quad * 4 + r;
                    Out[(size_t)row * H_ + col] = (__bf16)acc[mi][ni][r];
                }
            }
    } else {
        const int bb = m0 >> 11;
        const int t0 = m0 & (T_ - 1);
        #pragma unroll
        for (int ni = 0; ni < 4; ++ni)
            #pragma unroll
            for (int mi = 0; mi < 4; ++mi) {
                const int tok = t0 + wqm * 64 + mi * 16 + lr;
                #pragma unroll
                for (int r = 0; r < 4; ++r) {
                    const int h = wqn * 64 + ni * 16 + quad * 4 + r;
                    VtG[(size_t)bb * H_ * T_ + (size_t)h * T_ + tok] = (__bf16)acc[mi][ni][r];
                }
            }
    }
}

// ---------------- flash attention v3: balanced q-tile pairs ------------------
// grid (32, 16): x = batch (id%8 = b%8 -> all blocks of a batch share an XCD),
// y = qp. Block runs TWO 64-row q-tiles serially: qt=qp then qt=31-qp ->
// exactly 33 j-rounds for EVERY block: 8 waves/CU steady, no drain tail,
// co-resident block hides barrier stalls. 4 waves x 16 rows, swapped QK^T
// (lane holds one q-row), packed bf4 P writes, cross-segment K/V prefetch.
__global__ __launch_bounds__(256, 2) void flash_kernel(
    const __bf16* __restrict__ Qb, const __bf16* __restrict__ Kb,
    const __bf16* __restrict__ VtG, float* __restrict__ Out)
{
    __shared__ __bf16 Ks[64][136];   // [s][h]
    __shared__ __bf16 Vt[128][72];   // [h][s]
    __shared__ __bf16 Ps[64][72];    // [q][s], wave-private 16-row slabs

    const int b  = blockIdx.x;       // batch
    const int qp = blockIdx.y;       // 0..15 -> q-tiles {qp, 31-qp}
    const size_t kqbase = (size_t)b * T_ * H_;
    const size_t vbase  = (size_t)b * H_ * T_;

    const int tid  = threadIdx.x;    // 0..255
    const int lane = tid & 63;
    const int w    = tid >> 6;       // 0..3
    const int lr   = lane & 15;
    const int quad = lane >> 4;

    const float sc = 0.03125f * 1.4426950408889634f;   // C^-0.5 * log2(e)

    // staging coords: 256 threads x 4 chunks for K (64x128) and Vt (128x64)
    int kR[4], kC[4], vH[4], vS[4];
    #pragma unroll
    for (int i = 0; i < 4; i++) {
        const int u = tid + i * 256;
        kR[i] = u >> 4;  kC[i] = (u & 15) << 3;
        vH[i] = u >> 3;  vS[i] = (u & 7) << 3;
    }

    // preload tile j=0 (segment 0)
    bf8_t kr[4], vr[4];
    #pragma unroll
    for (int i = 0; i < 4; i++) {
        kr[i] = *(const bf8_t*)(Kb + kqbase + (size_t)kR[i] * H_ + kC[i]);
        vr[i] = *(const bf8_t*)(VtG + vbase + (size_t)vH[i] * T_ + vS[i]);
    }

    for (int seg = 0; seg < 2; ++seg) {
        const int qt   = seg ? (31 - qp) : qp;   // 64-row q-tile index
        const int jmax = qt;                      // causal: KV tiles 0..qt

        bf8_t qf[4];
        {
            const __bf16* qpr = Qb + kqbase + (size_t)(qt * 64 + w * 16 + lr) * H_ + quad * 8;
            #pragma unroll
            for (int ks = 0; ks < 4; ks++) qf[ks] = *(const bf8_t*)(qpr + ks * 32);
        }

        f4_t o[8];
        #pragma unroll
        for (int n = 0; n < 8; n++) o[n] = f4_t{0.f, 0.f, 0.f, 0.f};
        float ls = 0.f;

        for (int j = 0; j <= jmax; ++j) {
            __syncthreads();
            #pragma unroll
            for (int i = 0; i < 4; i++) {
                *(bf8_t*)&Ks[kR[i]][kC[i]] = kr[i];
                *(bf8_t*)&Vt[vH[i]][vS[i]] = vr[i];
            }
            __syncthreads();
            {   // prefetch next tile (or next segment's tile 0); hides under compute
                const int s0 = (j < jmax) ? (j + 1) * 64 : 0;
                #pragma unroll
                for (int i = 0; i < 4; i++) {
                    kr[i] = *(const bf8_t*)(Kb + kqbase + (size_t)(s0 + kR[i]) * H_ + kC[i]);
                    vr[i] = *(const bf8_t*)(VtG + vbase + (size_t)vH[i] * T_ + s0 + vS[i]);
                }
            }

            // QK^T swapped: s4[n][r] = S[k = j*64+n*16+quad*4+r][q = qt*64+w*16+lr]
            f4_t s4[4];
            #pragma unroll
            for (int n = 0; n < 4; n++) s4[n] = f4_t{0.f, 0.f, 0.f, 0.f};
            #pragma unroll
            for (int ks = 0; ks < 4; ks++)
                #pragma unroll
                for (int n = 0; n < 4; n++) {
                    bf8_t kf = *(const bf8_t*)&Ks[n * 16 + lr][ks * 32 + quad * 8];
                    s4[n] = __builtin_amdgcn_mfma_f32_16x16x32_bf16(kf, qf[ks], s4[n], 0, 0, 0);
                }

            // softmax (per-lane single q-row) + packed P write
            const bool dm = (j == jmax);          // diagonal tile for all waves
            const int qg = w * 16 + lr;           // q-row rel. to qt*64
            #pragma unroll
            for (int n = 0; n < 4; n++) {
                bf4_t pk;
                #pragma unroll
                for (int r = 0; r < 4; r++) {
                    float p = __builtin_exp2f(s4[n][r] * sc);
                    if (dm && (n * 16 + quad * 4 + r) > qg) p = 0.f;
                    ls += p;
                    pk[r] = (__bf16)p;
                }
                *(bf4_t*)&Ps[w * 16 + lr][n * 16 + quad * 4] = pk;
            }

            // PV: o[n] += P * V
            #pragma unroll
            for (int ks = 0; ks < 2; ks++) {
                bf8_t pfr = *(const bf8_t*)&Ps[w * 16 + lr][ks * 32 + quad * 8];
                #pragma unroll
                for (int n = 0; n < 8; n++) {
                    bf8_t vf = *(const bf8_t*)&Vt[n * 16 + lr][ks * 32 + quad * 8];
                    o[n] = __builtin_amdgcn_mfma_f32_16x16x32_bf16(pfr, vf, o[n], 0, 0, 0);
                }
            }
        }

        // rowsum inverse: lane holds sum for q-row lr (spread over quads)
        float v = ls;
        v += __shfl_xor(v, 16);
        v += __shfl_xor(v, 32);
        const float iv = 1.f / v;
        float inv[4];
        #pragma unroll
        for (int r = 0; r < 4; r++) inv[r] = __shfl(iv, quad * 4 + r);

        #pragma unroll
        for (int n = 0; n < 8; n++) {
            const int col = n * 16 + lr;
            #pragma unroll
            for (int r = 0; r < 4; r++) {
                const int row = qt * 64 + w * 16 + quad * 4 + r;
                Out[kqbase + (size_t)row * H_ + col] = o[n][r] * inv[r];
            }
        }
    }
}

extern "C" void kernel_launch(void* const* d_in, const int* in_sizes, int n_in,
                              void* d_out, int out_size, void* d_ws, size_t ws_size,
                              hipStream_t stream) {
    const float* x  = (const float*)d_in[0];
    const float* Wk = (const float*)d_in[1];
    const float* Wq = (const float*)d_in[2];
    const float* Wv = (const float*)d_in[3];
    float* out = (float*)d_out;

    const size_t n_kqv = (size_t)B_ * T_ * H_;
    __bf16* Kb  = (__bf16*)d_ws;
    __bf16* Qb  = Kb + n_kqv;
    __bf16* VtG = Qb + n_kqv;
    __bf16* Wr  = VtG + n_kqv;   // 768 KB more

    wconv_kernel<<<dim3(192), 256, 0, stream>>>(Wk, Wq, Wv, Wr);
    proj_kernel<<<dim3(512 * 3), 256, 0, stream>>>(x, Wr, Kb, Qb, VtG);
    flash_kernel<<<dim3(32, 16), 256, 0, stream>>>(Qb, Kb, VtG, out);
}